// Round 13
// baseline (499.184 us; speedup 1.0000x reference)
//
#include <hip/hip_runtime.h>
#include <hip/hip_bf16.h>

// Problem constants (fixed by setup_inputs)
#define B_   4
#define N_   4096
#define KNN_ 32
#define KK_  64          // 2*k
#define MTOT 1048576     // B*N*KK
#define BN_EPS 1e-3f

typedef unsigned int u32;
typedef unsigned long long u64;
typedef __attribute__((ext_vector_type(8))) short bf16x8;
typedef __attribute__((ext_vector_type(4))) float f32x4;

__device__ __forceinline__ ushort f2bf_bits(float f) {   // RNE, finite inputs only
    u32 b = __float_as_uint(f);
    b += 0x7fffu + ((b >> 16) & 1u);
    return (ushort)(b >> 16);
}

__device__ __forceinline__ float med3f(float a, float b, float c) {
    return __builtin_amdgcn_fmed3f(a, b, c);
}

// Ranking key with hoisted |c|^2 (czw.y) and premultiplied -2q (3 FMA).
__device__ __forceinline__ float rank_e3(float cx, float cy, float2 zw,
                                         float m2x, float m2y, float m2z) {
    return fmaf(m2x, cx, fmaf(m2y, cy, fmaf(m2z, zw.x, zw.y)));
}

__device__ __forceinline__ u32 ordkey(float f) {         // monotone bijection f32->u32
    u32 u = __float_as_uint(f);
    return u ^ (u32)(((int)u >> 31) | 0x80000000);
}
__device__ __forceinline__ float ordinv(u32 k) {         // exact inverse of ordkey
    u32 u = (k & 0x80000000u) ? (k ^ 0x80000000u) : ~k;
    return __uint_as_float(u);
}

// ---------------------------------------------------------------------------
// K1: dual KNN (r23 verbatim — 196 us measured, parked: VALU floor ~114 us,
// remaining levers <5% each; ballot/scalar chains bound it, not FMAs).
// ---------------------------------------------------------------------------
__global__ __launch_bounds__(512, 2) void knn_kernel(
    const float* __restrict__ p1, const float* __restrict__ p2,
    float* __restrict__ feats, float* __restrict__ mom)
{
    __shared__ float2 cxy[N_];                   // 32 KB (part[] overlaps at end)
    __shared__ float2 czw[N_];                   // 32 KB: (z, |c|^2)

    const int tid  = threadIdx.x;
    const int wave = tid >> 6, lane = tid & 63;
    const int pb    = blockIdx.x >> 6;           // 0..7
    const int chunk = blockIdx.x & 63;           // 0..63
    const int pr = pb >> 2, b = pb & 3;
    const int start = chunk * 64;

    const float* srcb = (pr ? p2 : p1) + (size_t)b * 3 * N_;
    for (int n = tid; n < N_; n += 512) {
        float x = srcb[n], y = srcb[N_ + n], z = srcb[2*N_ + n];
        cxy[n] = make_float2(x, y);
        czw[n] = make_float2(z, fmaf(x, x, fmaf(y, y, z * z)));
    }
    __syncthreads();

    const float* p1b = p1 + (size_t)b * 3 * N_;
    const u64 below = (1ull << lane) - 1ull;
    const float FMAX = 3.402823466e+38f;

    for (int n = start + wave; n < start + 64; n += 8) {
        float qx, qy, qz;
        if (pr == 0) { float2 q = cxy[n]; qx = q.x; qy = q.y; qz = czw[n].x; }
        else         { qx = p1b[n]; qy = p1b[N_ + n]; qz = p1b[2*N_ + n]; }
        const float m2x = -2.0f * qx, m2y = -2.0f * qy, m2z = -2.0f * qz;

        float keys[64];
        float A0 = FMAX, A1 = FMAX, A2 = FMAX, A3 = FMAX;
        float B0 = FMAX, B1 = FMAX, B2 = FMAX, B3 = FMAX;
        #pragma unroll
        for (int j = 0; j < 32; ++j) {
            {
                float2 c  = cxy[j * 64 + lane];
                float2 zw = czw[j * 64 + lane];
                float  e  = rank_e3(c.x, c.y, zw, m2x, m2y, m2z);
                keys[j] = e;
                A3 = med3f(e, A2, A3);
                A2 = med3f(e, A1, A2);
                A1 = med3f(e, A0, A1);
                A0 = fminf(A0, e);
            }
            {
                float2 c  = cxy[(j + 32) * 64 + lane];
                float2 zw = czw[(j + 32) * 64 + lane];
                float  e  = rank_e3(c.x, c.y, zw, m2x, m2y, m2z);
                keys[j + 32] = e;
                B3 = med3f(e, B2, B3);
                B2 = med3f(e, B1, B2);
                B1 = med3f(e, B0, B1);
                B0 = fminf(B0, e);
            }
        }
        #pragma unroll
        for (int m = 0; m < 4; ++m) {
            float x = (m == 0) ? B0 : (m == 1) ? B1 : (m == 2) ? B2 : B3;
            A3 = med3f(x, A2, A3);
            A2 = med3f(x, A1, A2);
            A1 = med3f(x, A0, A1);
            A0 = fminf(A0, x);
        }
        u32 k0 = ordkey(A0), k1 = ordkey(A1), k2 = ordkey(A2), k3 = ordkey(A3);

        u32 mn = k0, mx = k3;
        #pragma unroll
        for (int off = 1; off < 64; off <<= 1) {
            mn = min(mn, (u32)__shfl_xor((int)mn, off, 64));
            mx = max(mx, (u32)__shfl_xor((int)mx, off, 64));
        }
        u32 lo = mn, hi = mx;
        while (lo < hi) {
            u32 mid = lo + ((hi - lo) >> 1);
            int c = __popcll(__ballot(k0 <= mid)) + __popcll(__ballot(k1 <= mid))
                  + __popcll(__ballot(k2 <= mid)) + __popcll(__ballot(k3 <= mid));
            if (c >= 32) hi = mid; else lo = mid + 1;
        }
        u32 T = lo;
        float Tf = ordinv(T);

        int nl;
        if (__ballot(A3 <= Tf) == 0ull) {
            nl = __popcll(__ballot(A0 < Tf)) + __popcll(__ballot(A1 < Tf))
               + __popcll(__ballot(A2 < Tf)) + __popcll(__ballot(A3 < Tf));
        } else {
            nl = 0;
            #pragma unroll
            for (int j = 0; j < 64; ++j) nl += __popcll(__ballot(keys[j] < Tf));
            if (nl > 31) {                  // kept-4 truncated (rare)
                u32 lo2 = 0u, hi2 = T;
                while (lo2 < hi2) {
                    u32 mid = lo2 + ((hi2 - lo2) >> 1);
                    float mf = ordinv(mid);
                    int c = 0;
                    #pragma unroll
                    for (int j = 0; j < 64; ++j) c += __popcll(__ballot(keys[j] <= mf));
                    if (c >= 32) hi2 = mid; else lo2 = mid + 1;
                }
                T = lo2;
                Tf = ordinv(T);
                nl = 0;
                #pragma unroll
                for (int j = 0; j < 64; ++j) nl += __popcll(__ballot(keys[j] < Tf));
            }
        }
        const int need_eq = 32 - nl;        // >= 1; ties resolved by candidate index

        float* fout = feats + ((size_t)(b * N_ + n) * KK_ + pr * KNN_) * 4;
        int base = 0, eq_seen = 0;
        #pragma unroll
        for (int j = 0; j < 64; ++j) {
            float e = keys[j];
            bool lt = e < Tf;
            bool eq = e == Tf;
            u64 mlt = __ballot(lt);
            u64 meq = __ballot(eq);
            if (mlt | meq) {
                int slot = -1;
                if (lt) slot = base + __popcll(mlt & below);
                else if (eq) {
                    int es = eq_seen + __popcll(meq & below);
                    if (es < need_eq) slot = nl + es;
                }
                if (slot >= 0) {
                    float2 c  = cxy[j * 64 + lane];
                    float2 zw = czw[j * 64 + lane];
                    float rx = c.x - qx, ry = c.y - qy, rz = zw.x - qz;
                    float dist = sqrtf(fmaf(rx, rx, fmaf(ry, ry, rz*rz)));
                    *(float4*)(fout + slot * 4) = make_float4(rx, ry, rz, dist);
                }
                base    += __popcll(mlt);
                eq_seen += __popcll(meq);
            }
        }
    }

    // ---- epilogue: moments over this block's own feats (keys dead here) ----
    __syncthreads();
    float mm[14];
    #pragma unroll
    for (int s = 0; s < 14; ++s) mm[s] = 0.f;
    const float4* fb = (const float4*)feats
                     + ((size_t)(b * N_ + start) * KK_ + pr * KNN_);
    for (int idx = tid; idx < 64 * 32; idx += 512) {
        int row = idx >> 5, col = idx & 31;
        float4 f = fb[(size_t)row * KK_ + col];
        float rx = f.x, ry = f.y, rz = f.z, dist = f.w;
        mm[0] += rx; mm[1] += ry; mm[2] += rz; mm[3] += dist;
        mm[4]  = fmaf(rx, rx, mm[4]);   mm[5]  = fmaf(rx, ry, mm[5]);
        mm[6]  = fmaf(rx, rz, mm[6]);   mm[7]  = fmaf(rx, dist, mm[7]);
        mm[8]  = fmaf(ry, ry, mm[8]);   mm[9]  = fmaf(ry, rz, mm[9]);
        mm[10] = fmaf(ry, dist, mm[10]); mm[11] = fmaf(rz, rz, mm[11]);
        mm[12] = fmaf(rz, dist, mm[12]); mm[13] = fmaf(dist, dist, mm[13]);
    }
    #pragma unroll
    for (int s = 0; s < 14; ++s) {
        #pragma unroll
        for (int off = 1; off < 64; off <<= 1) mm[s] += __shfl_xor(mm[s], off, 64);
    }
    float* partf = (float*)cxy;       // cxy dead; barrier above orders reads
    if (lane == 0) {
        #pragma unroll
        for (int s = 0; s < 14; ++s) partf[wave * 14 + s] = mm[s];
    }
    __syncthreads();
    if (tid < 14) {
        float v = 0.f;
        #pragma unroll
        for (int w8 = 0; w8 < 8; ++w8) v += partf[w8 * 14 + tid];
        atomicAdd(&mom[tid * 16], v);    // one cacheline per counter
    }
}

// ---------------------------------------------------------------------------
// K3' conv2_stats (r24): conv2_mfma MINUS the 128 MB y2F write. y2 is now
// recomputed from feats (16 MB) by K4'/K5' — r18 only dropped the x3 write
// (kept 2x y2 reads, net loss); dropping ALL y2/x3 HBM traffic (512 MB ->
// 48 MB) is the actual win since recompute costs ~4 us MFMA + trivial VALU.
// ---------------------------------------------------------------------------
__global__ __launch_bounds__(256) void conv2_stats(
    const float* __restrict__ feats,
    const float* __restrict__ W1,
    const float* __restrict__ g1, const float* __restrict__ be1,
    const float* __restrict__ W2,
    const float* __restrict__ mom,
    float* __restrict__ s2S, float* __restrict__ s2Q)
{
    __shared__ float statS[64], statQ[64];
    const int tid = threadIdx.x;
    const int wid = tid >> 6, l = tid & 63, q = l >> 4, i = l & 15;
    if (tid < 64) { statS[tid] = 0.f; statQ[tid] = 0.f; }

    const float invM = 1.0f / MTOT;
    const float M0 = mom[0*16], M1 = mom[1*16], M2 = mom[2*16], M3 = mom[3*16];
    const float Sxx = mom[4*16],  Sxy = mom[5*16],  Sxz = mom[6*16],  Sxd = mom[7*16];
    const float Syy = mom[8*16],  Syz = mom[9*16],  Syd = mom[10*16];
    const float Szz = mom[11*16], Szd = mom[12*16], Sdd = mom[13*16];

    float4 w1f[16];
    float  c1v[16];
    #pragma unroll
    for (int h = 0; h < 2; ++h)
      #pragma unroll
      for (int j = 0; j < 8; ++j) {
        int ci = h*32 + q*8 + j;
        float w0 = W1[ci*4+0], w1 = W1[ci*4+1], w2 = W1[ci*4+2], w3 = W1[ci*4+3];
        float meanf = (w0*M0 + w1*M1 + w2*M2 + w3*M3) * invM;
        float qq = w0*(w0*Sxx + 2.f*(w1*Sxy + w2*Sxz + w3*Sxd))
                 + w1*(w1*Syy + 2.f*(w2*Syz + w3*Syd))
                 + w2*(w2*Szz + 2.f*w3*Szd)
                 + w3*w3*Sdd;
        float var = qq * invM - meanf * meanf;
        float sc  = g1[ci] * rsqrtf(var + BN_EPS);
        w1f[h*8+j] = make_float4(sc*w0, sc*w1, sc*w2, sc*w3);
        c1v[h*8+j] = fmaf(-sc, meanf, be1[ci]);
      }
    bf16x8 a2[4][2];
    #pragma unroll
    for (int t = 0; t < 4; ++t)
      #pragma unroll
      for (int h = 0; h < 2; ++h)
        #pragma unroll
        for (int j = 0; j < 8; ++j)
          a2[t][h][j] = (short)f2bf_bits(W2[(t*16 + i)*64 + h*32 + q*8 + j]);

    float ssum[16], ssq[16];
    #pragma unroll
    for (int s = 0; s < 16; ++s) { ssum[s] = 0.f; ssq[s] = 0.f; }
    __syncthreads();

    for (int r16 = 0; r16 < 16; ++r16) {
        const int row = blockIdx.x * 16 + r16;
        float4 f = ((const float4*)feats)[row*64 + wid*16 + i];
        bf16x8 xb[2];
        #pragma unroll
        for (int h = 0; h < 2; ++h)
          #pragma unroll
          for (int j = 0; j < 8; ++j) {
            float4 w = w1f[h*8+j];
            float x = fmaxf(fmaf(w.x, f.x, fmaf(w.y, f.y, fmaf(w.z, f.z, fmaf(w.w, f.w, c1v[h*8+j])))), 0.f);
            xb[h][j] = (short)f2bf_bits(x);
          }
        f32x4 acc[4];
        #pragma unroll
        for (int t = 0; t < 4; ++t) acc[t] = (f32x4){0.f,0.f,0.f,0.f};
        #pragma unroll
        for (int t = 0; t < 4; ++t) {
            acc[t] = __builtin_amdgcn_mfma_f32_16x16x32_bf16(a2[t][0], xb[0], acc[t], 0, 0, 0);
            acc[t] = __builtin_amdgcn_mfma_f32_16x16x32_bf16(a2[t][1], xb[1], acc[t], 0, 0, 0);
        }
        #pragma unroll
        for (int t = 0; t < 4; ++t)
          #pragma unroll
          for (int reg = 0; reg < 4; ++reg) {
            float y = acc[t][reg];
            ssum[t*4+reg] += y;
            ssq[t*4+reg]  = fmaf(y, y, ssq[t*4+reg]);
          }
    }
    #pragma unroll
    for (int s = 0; s < 16; ++s) {
        #pragma unroll
        for (int off = 1; off < 16; off <<= 1) {
            ssum[s] += __shfl_xor(ssum[s], off, 64);
            ssq[s]  += __shfl_xor(ssq[s],  off, 64);
        }
    }
    if (i == 0) {
        #pragma unroll
        for (int s = 0; s < 16; ++s) {
            int co = (s >> 2)*16 + q*4 + (s & 3);
            atomicAdd(&statS[co], ssum[s]);
            atomicAdd(&statQ[co], ssq[s]);
        }
    }
    __syncthreads();
    if (tid < 64) { atomicAdd(&s2S[tid], statS[tid]); atomicAdd(&s2Q[tid], statQ[tid]); }
}

// ---------------------------------------------------------------------------
// Shared stage-1 note (K4'/K5'): recompute x1 (bn1-folded W1 from LDS tables)
// -> y2 via MFMA -> x3 = relu(bn2(bf16roundtrip(y2))) — BIT-IDENTICAL to the
// old store/load path (f32->bf16->f32->bn2->relu->bf16 preserved). x3 frags
// land in an 8 KB LDS row tile at the SAME addresses conv2 used on y2F, so
// the stage-2 reads reuse the verified frag-layout arithmetic unchanged.
// ---------------------------------------------------------------------------

// K4': fused conv3 stats — feats -> x1 -> y2 -> x3 (LDS) -> y3 stats.
__global__ __launch_bounds__(256) void conv3_stats_f(
    const float* __restrict__ feats,
    const float* __restrict__ W1,
    const float* __restrict__ g1, const float* __restrict__ be1,
    const float* __restrict__ W2,
    const float* __restrict__ mom,
    const float* __restrict__ g2, const float* __restrict__ be2,
    const float* __restrict__ W3,
    const float* __restrict__ s2S, const float* __restrict__ s2Q,
    float* __restrict__ s3S, float* __restrict__ s3Q)
{
    __shared__ ushort x3L[4096];                 // 8 KB: one row's x3 frags
    __shared__ float  statS[128], statQ[128];
    __shared__ float4 w1L[64];
    __shared__ float  c1L[64], sc2L[64], sh2L[64];

    const int tid = threadIdx.x;
    const int w = tid >> 6, l = tid & 63, q = l >> 4, i = l & 15;
    const int ph = w >> 1, oh = w & 1, wid = w;
    if (tid < 128) { statS[tid] = 0.f; statQ[tid] = 0.f; }

    if (tid < 64) {                              // bn1 + bn2 folds -> LDS
        const int ci = tid;
        const float invM = 1.0f / MTOT;
        float M0 = mom[0*16], M1 = mom[1*16], M2 = mom[2*16], M3 = mom[3*16];
        float Sxx = mom[4*16],  Sxy = mom[5*16],  Sxz = mom[6*16],  Sxd = mom[7*16];
        float Syy = mom[8*16],  Syz = mom[9*16],  Syd = mom[10*16];
        float Szz = mom[11*16], Szd = mom[12*16], Sdd = mom[13*16];
        float w0 = W1[ci*4+0], w1 = W1[ci*4+1], w2 = W1[ci*4+2], w3 = W1[ci*4+3];
        float meanf = (w0*M0 + w1*M1 + w2*M2 + w3*M3) * invM;
        float qq = w0*(w0*Sxx + 2.f*(w1*Sxy + w2*Sxz + w3*Sxd))
                 + w1*(w1*Syy + 2.f*(w2*Syz + w3*Syd))
                 + w2*(w2*Szz + 2.f*w3*Szd)
                 + w3*w3*Sdd;
        float var = qq * invM - meanf * meanf;
        float sc  = g1[ci] * rsqrtf(var + BN_EPS);
        w1L[ci] = make_float4(sc*w0, sc*w1, sc*w2, sc*w3);
        c1L[ci] = fmaf(-sc, meanf, be1[ci]);
        float m2  = s2S[ci] * invM;
        float v2  = s2Q[ci] * invM - m2 * m2;
        float sc2 = g2[ci] * rsqrtf(v2 + BN_EPS);
        sc2L[ci] = sc2;
        sh2L[ci] = fmaf(-sc2, m2, be2[ci]);
    }

    bf16x8 a2[4][2], a3[4][2];
    #pragma unroll
    for (int t = 0; t < 4; ++t)
      #pragma unroll
      for (int h = 0; h < 2; ++h)
        #pragma unroll
        for (int j = 0; j < 8; ++j) {
          a2[t][h][j] = (short)f2bf_bits(W2[(t*16 + i)*64 + h*32 + q*8 + j]);
          a3[t][h][j] = (short)f2bf_bits(W3[((oh*4 + t)*16 + i)*64 + h*32 + q*8 + j]);
        }

    float ssum[16], ssq[16];
    #pragma unroll
    for (int s = 0; s < 16; ++s) { ssum[s] = 0.f; ssq[s] = 0.f; }
    __syncthreads();

    for (int r16 = 0; r16 < 16; ++r16) {
        const int row = blockIdx.x * 16 + r16;
        // ---- stage 1: y2 for positions wid*16..+15, x3 -> LDS ----
        float4 f = ((const float4*)feats)[row*64 + wid*16 + i];
        bf16x8 xb[2];
        #pragma unroll
        for (int h = 0; h < 2; ++h)
          #pragma unroll
          for (int j = 0; j < 8; ++j) {
            float4 wv = w1L[h*32 + q*8 + j];
            float c1 = c1L[h*32 + q*8 + j];
            float x = fmaxf(fmaf(wv.x, f.x, fmaf(wv.y, f.y, fmaf(wv.z, f.z, fmaf(wv.w, f.w, c1)))), 0.f);
            xb[h][j] = (short)f2bf_bits(x);
          }
        f32x4 acc[4];
        #pragma unroll
        for (int t = 0; t < 4; ++t) acc[t] = (f32x4){0.f,0.f,0.f,0.f};
        #pragma unroll
        for (int t = 0; t < 4; ++t) {
            acc[t] = __builtin_amdgcn_mfma_f32_16x16x32_bf16(a2[t][0], xb[0], acc[t], 0, 0, 0);
            acc[t] = __builtin_amdgcn_mfma_f32_16x16x32_bf16(a2[t][1], xb[1], acc[t], 0, 0, 0);
        }
        #pragma unroll
        for (int t = 0; t < 4; ++t) {
            ushort o[4];
            #pragma unroll
            for (int reg = 0; reg < 4; ++reg) {
                ushort yb = f2bf_bits(acc[t][reg]);           // y2 -> bf16 (as stored before)
                float xf = __uint_as_float(((u32)yb) << 16);  // bf16 -> f32
                float x3 = fmaxf(fmaf(sc2L[t*16 + q*4 + reg], xf, sh2L[t*16 + q*4 + reg]), 0.f);
                o[reg] = f2bf_bits(x3);
            }
            uint2 pk;
            pk.x = (u32)o[0] | ((u32)o[1] << 16);
            pk.y = (u32)o[2] | ((u32)o[3] << 16);
            *(uint2*)&x3L[wid*1024 + t*256 + q*64 + i*4] = pk;
        }
        __syncthreads();   // x3 row tile complete

        // ---- stage 2: wave (ph,oh): y3 for 32 pos x 64 out-ch, stats ----
        const ushort* rp0 = x3L + (2*ph)*1024 + q*128 + i*4;
        const ushort* rp1 = rp0 + 1024;
        uint2 a00 = *(const uint2*)(rp0);       uint2 a01 = *(const uint2*)(rp0 + 64);
        uint2 a10 = *(const uint2*)(rp0 + 512); uint2 a11 = *(const uint2*)(rp0 + 576);
        uint2 b00 = *(const uint2*)(rp1);       uint2 b01 = *(const uint2*)(rp1 + 64);
        uint2 b10 = *(const uint2*)(rp1 + 512); uint2 b11 = *(const uint2*)(rp1 + 576);
        uint4 va0 = make_uint4(a00.x, a00.y, a01.x, a01.y);
        uint4 va1 = make_uint4(a10.x, a10.y, a11.x, a11.y);
        uint4 vc0 = make_uint4(b00.x, b00.y, b01.x, b01.y);
        uint4 vc1 = make_uint4(b10.x, b10.y, b11.x, b11.y);
        bf16x8 xa0 = *(bf16x8*)&va0, xa1 = *(bf16x8*)&va1;
        bf16x8 xc0 = *(bf16x8*)&vc0, xc1 = *(bf16x8*)&vc1;
        #pragma unroll
        for (int t = 0; t < 4; ++t) {
            f32x4 A = (f32x4){0.f,0.f,0.f,0.f};
            A = __builtin_amdgcn_mfma_f32_16x16x32_bf16(a3[t][0], xa0, A, 0, 0, 0);
            A = __builtin_amdgcn_mfma_f32_16x16x32_bf16(a3[t][1], xa1, A, 0, 0, 0);
            f32x4 Bv = (f32x4){0.f,0.f,0.f,0.f};
            Bv = __builtin_amdgcn_mfma_f32_16x16x32_bf16(a3[t][0], xc0, Bv, 0, 0, 0);
            Bv = __builtin_amdgcn_mfma_f32_16x16x32_bf16(a3[t][1], xc1, Bv, 0, 0, 0);
            #pragma unroll
            for (int reg = 0; reg < 4; ++reg) {
                float ya = A[reg], yb = Bv[reg];
                ssum[t*4+reg] += ya + yb;
                ssq[t*4+reg]  = fmaf(ya, ya, fmaf(yb, yb, ssq[t*4+reg]));
            }
        }
        __syncthreads();   // x3L free for next row
    }
    #pragma unroll
    for (int s = 0; s < 16; ++s) {
        #pragma unroll
        for (int off = 1; off < 16; off <<= 1) {
            ssum[s] += __shfl_xor(ssum[s], off, 64);
            ssq[s]  += __shfl_xor(ssq[s],  off, 64);
        }
    }
    if (i == 0) {
        #pragma unroll
        for (int s = 0; s < 16; ++s) {
            int co = oh*64 + (s >> 2)*16 + q*4 + (s & 3);
            atomicAdd(&statS[co], ssum[s]);
            atomicAdd(&statQ[co], ssq[s]);
        }
    }
    __syncthreads();
    if (tid < 128) { atomicAdd(&s3S[tid], statS[tid]); atomicAdd(&s3Q[tid], statQ[tid]); }
}

// K5': fused conv3 final — feats -> x1 -> y2 -> x3 (LDS) -> y3 -> softmax out.
__global__ __launch_bounds__(256) void conv3_final_f(
    const float* __restrict__ feats,
    const float* __restrict__ W1,
    const float* __restrict__ g1, const float* __restrict__ be1,
    const float* __restrict__ W2,
    const float* __restrict__ mom,
    const float* __restrict__ g2, const float* __restrict__ be2,
    const float* __restrict__ W3,
    const float* __restrict__ s2S, const float* __restrict__ s2Q,
    const float* __restrict__ g3, const float* __restrict__ be3,
    const float* __restrict__ s3S, const float* __restrict__ s3Q,
    const float* __restrict__ p1, float* __restrict__ outp)
{
    __shared__ ushort x3L[4096];                 // 8 KB
    __shared__ float4 w1L[64];
    __shared__ float  c1L[64], sc2L[64], sh2L[64];
    __shared__ float  sc3L[128], sh3L[128];
    __shared__ float  s2L[2][2][64];             // [row parity][oh][position]

    const int tid = threadIdx.x;
    const int w = tid >> 6, l = tid & 63, q = l >> 4, i = l & 15;
    const int ph = w >> 1, oh = w & 1, wid = w;

    if (tid < 64) {                              // bn1 + bn2 folds -> LDS
        const int ci = tid;
        const float invM = 1.0f / MTOT;
        float M0 = mom[0*16], M1 = mom[1*16], M2 = mom[2*16], M3 = mom[3*16];
        float Sxx = mom[4*16],  Sxy = mom[5*16],  Sxz = mom[6*16],  Sxd = mom[7*16];
        float Syy = mom[8*16],  Syz = mom[9*16],  Syd = mom[10*16];
        float Szz = mom[11*16], Szd = mom[12*16], Sdd = mom[13*16];
        float w0 = W1[ci*4+0], w1 = W1[ci*4+1], w2 = W1[ci*4+2], w3 = W1[ci*4+3];
        float meanf = (w0*M0 + w1*M1 + w2*M2 + w3*M3) * invM;
        float qq = w0*(w0*Sxx + 2.f*(w1*Sxy + w2*Sxz + w3*Sxd))
                 + w1*(w1*Syy + 2.f*(w2*Syz + w3*Syd))
                 + w2*(w2*Szz + 2.f*w3*Szd)
                 + w3*w3*Sdd;
        float var = qq * invM - meanf * meanf;
        float sc  = g1[ci] * rsqrtf(var + BN_EPS);
        w1L[ci] = make_float4(sc*w0, sc*w1, sc*w2, sc*w3);
        c1L[ci] = fmaf(-sc, meanf, be1[ci]);
        float m2  = s2S[ci] * invM;
        float v2  = s2Q[ci] * invM - m2 * m2;
        float sc2 = g2[ci] * rsqrtf(v2 + BN_EPS);
        sc2L[ci] = sc2;
        sh2L[ci] = fmaf(-sc2, m2, be2[ci]);
    }
    if (tid < 128) {                             // bn3 fold -> LDS
        const float invM = 1.0f / MTOT;
        float m  = s3S[tid] * invM;
        float v  = s3Q[tid] * invM - m * m;
        float sc = g3[tid] * rsqrtf(v + BN_EPS);
        sc3L[tid] = sc;
        sh3L[tid] = fmaf(-sc, m, be3[tid]);
    }

    bf16x8 a2[4][2], a3[4][2];
    #pragma unroll
    for (int t = 0; t < 4; ++t)
      #pragma unroll
      for (int h = 0; h < 2; ++h)
        #pragma unroll
        for (int j = 0; j < 8; ++j) {
          a2[t][h][j] = (short)f2bf_bits(W2[(t*16 + i)*64 + h*32 + q*8 + j]);
          a3[t][h][j] = (short)f2bf_bits(W3[((oh*4 + t)*16 + i)*64 + h*32 + q*8 + j]);
        }
    __syncthreads();

    for (int r16 = 0; r16 < 16; ++r16) {
        const int row = blockIdx.x * 16 + r16;
        // ---- stage 1: y2 for positions wid*16..+15, x3 -> LDS ----
        float4 f = ((const float4*)feats)[row*64 + wid*16 + i];
        bf16x8 xb[2];
        #pragma unroll
        for (int h = 0; h < 2; ++h)
          #pragma unroll
          for (int j = 0; j < 8; ++j) {
            float4 wv = w1L[h*32 + q*8 + j];
            float c1 = c1L[h*32 + q*8 + j];
            float x = fmaxf(fmaf(wv.x, f.x, fmaf(wv.y, f.y, fmaf(wv.z, f.z, fmaf(wv.w, f.w, c1)))), 0.f);
            xb[h][j] = (short)f2bf_bits(x);
          }
        f32x4 acc[4];
        #pragma unroll
        for (int t = 0; t < 4; ++t) acc[t] = (f32x4){0.f,0.f,0.f,0.f};
        #pragma unroll
        for (int t = 0; t < 4; ++t) {
            acc[t] = __builtin_amdgcn_mfma_f32_16x16x32_bf16(a2[t][0], xb[0], acc[t], 0, 0, 0);
            acc[t] = __builtin_amdgcn_mfma_f32_16x16x32_bf16(a2[t][1], xb[1], acc[t], 0, 0, 0);
        }
        #pragma unroll
        for (int t = 0; t < 4; ++t) {
            ushort o[4];
            #pragma unroll
            for (int reg = 0; reg < 4; ++reg) {
                ushort yb = f2bf_bits(acc[t][reg]);
                float xf = __uint_as_float(((u32)yb) << 16);
                float x3 = fmaxf(fmaf(sc2L[t*16 + q*4 + reg], xf, sh2L[t*16 + q*4 + reg]), 0.f);
                o[reg] = f2bf_bits(x3);
            }
            uint2 pk;
            pk.x = (u32)o[0] | ((u32)o[1] << 16);
            pk.y = (u32)o[2] | ((u32)o[3] << 16);
            *(uint2*)&x3L[wid*1024 + t*256 + q*64 + i*4] = pk;
        }
        __syncthreads();   // x3 row tile complete

        // ---- stage 2: wave (ph,oh): bn3 channel-max over its half ----
        #pragma unroll
        for (int pt2 = 0; pt2 < 2; ++pt2) {
            const int pt = 2*ph + pt2;
            const ushort* rp = x3L + pt*1024 + q*128 + i*4;
            uint2 u00 = *(const uint2*)(rp);       uint2 u01 = *(const uint2*)(rp + 64);
            uint2 u10 = *(const uint2*)(rp + 512); uint2 u11 = *(const uint2*)(rp + 576);
            uint4 v0 = make_uint4(u00.x, u00.y, u01.x, u01.y);
            uint4 v1 = make_uint4(u10.x, u10.y, u11.x, u11.y);
            bf16x8 xb0 = *(bf16x8*)&v0, xb1 = *(bf16x8*)&v1;
            float mx = -3.4e38f;
            #pragma unroll
            for (int t = 0; t < 4; ++t) {
                f32x4 a = (f32x4){0.f,0.f,0.f,0.f};
                a = __builtin_amdgcn_mfma_f32_16x16x32_bf16(a3[t][0], xb0, a, 0, 0, 0);
                a = __builtin_amdgcn_mfma_f32_16x16x32_bf16(a3[t][1], xb1, a, 0, 0, 0);
                const int co = oh*64 + t*16 + q*4;
                float4 s4 = *(const float4*)&sc3L[co];
                float4 h4 = *(const float4*)&sh3L[co];
                mx = fmaxf(mx, fmaf(s4.x, a[0], h4.x));
                mx = fmaxf(mx, fmaf(s4.y, a[1], h4.y));
                mx = fmaxf(mx, fmaf(s4.z, a[2], h4.z));
                mx = fmaxf(mx, fmaf(s4.w, a[3], h4.w));
            }
            mx = fmaxf(mx, __shfl_xor(mx, 16, 64));
            mx = fmaxf(mx, __shfl_xor(mx, 32, 64));
            if (q == 0) s2L[r16 & 1][oh][pt*16 + i] = mx;
        }
        __syncthreads();   // s2L ready; x3L reads drained (safe to overwrite)

        if (w == 0) {
            float sc = fmaxf(fmaxf(s2L[r16 & 1][0][l], s2L[r16 & 1][1][l]), 0.f);
            float m2 = sc;
            #pragma unroll
            for (int off = 1; off < 64; off <<= 1) m2 = fmaxf(m2, __shfl_xor(m2, off, 64));
            float e = __expf(sc - m2);
            float se = e;
            #pragma unroll
            for (int off = 1; off < 64; off <<= 1) se += __shfl_xor(se, off, 64);
            float wgt = e / se;
            const int bb = row >> 12, n = row & 4095;
            float qx = p1[(size_t)bb*3*N_ + n];
            float qy = p1[(size_t)bb*3*N_ + N_ + n];
            float qz = p1[(size_t)bb*3*N_ + 2*N_ + n];
            float4 f4 = ((const float4*)feats)[row*64 + l];
            float ox = wgt * (f4.x + qx), oy = wgt * (f4.y + qy), oz = wgt * (f4.z + qz);
            #pragma unroll
            for (int off = 1; off < 64; off <<= 1) {
                ox += __shfl_xor(ox, off, 64);
                oy += __shfl_xor(oy, off, 64);
                oz += __shfl_xor(oz, off, 64);
            }
            if (l == 0) {
                outp[bb*3*N_ + 0*N_ + n] = ox;
                outp[bb*3*N_ + 1*N_ + n] = oy;
                outp[bb*3*N_ + 2*N_ + n] = oz;
            }
        }
    }
}

// ---------------------------------------------------------------------------
extern "C" void kernel_launch(void* const* d_in, const int* in_sizes, int n_in,
                              void* d_out, int out_size, void* d_ws, size_t ws_size,
                              hipStream_t stream)
{
    const float* p1  = (const float*)d_in[0];
    const float* p2  = (const float*)d_in[1];
    // d_in[2] = k (always 32), d_in[3] = t (unused by reference)
    const float* W1  = (const float*)d_in[4];
    const float* g1  = (const float*)d_in[6];
    const float* be1 = (const float*)d_in[7];
    const float* W2  = (const float*)d_in[8];
    const float* g2  = (const float*)d_in[10];
    const float* be2 = (const float*)d_in[11];
    const float* W3  = (const float*)d_in[12];
    const float* g3  = (const float*)d_in[14];
    const float* be3 = (const float*)d_in[15];
    // b1 cancels through bn1 (moment fold); b2/b3 cancel through bn2/bn3.

    char* ws = (char*)d_ws;
    const size_t OFF_FEATS = 4096;
    const size_t NEEDED    = OFF_FEATS + (size_t)MTOT * 4 * 4;   // 16 MB feats only
    if (ws_size < NEEDED) return;  // fail visibly (wrong output) rather than fault

    float* s2S = (float*)(ws + 512);  float* s2Q = (float*)(ws + 768);
    float* s3S = (float*)(ws + 1024); float* s3Q = (float*)(ws + 1536);
    float* mom = (float*)(ws + 2048);            // 14 counters, 64-B stride each
    float* feats = (float*)(ws + OFF_FEATS);

    hipMemsetAsync(ws, 0, 4096, stream);  // zero stats + padded moment counters

    knn_kernel<<<512, 512, 0, stream>>>(p1, p2, feats, mom);
    conv2_stats<<<1024, 256, 0, stream>>>(feats, W1, g1, be1, W2, mom, s2S, s2Q);
    conv3_stats_f<<<1024, 256, 0, stream>>>(feats, W1, g1, be1, W2, mom,
                                            g2, be2, W3, s2S, s2Q, s3S, s3Q);
    conv3_final_f<<<1024, 256, 0, stream>>>(feats, W1, g1, be1, W2, mom,
                                            g2, be2, W3, s2S, s2Q,
                                            g3, be3, s3S, s3Q, p1,
                                            (float*)d_out);
}

// Round 14
// 436.571 us; speedup vs baseline: 1.1434x; 1.1434x over previous
//
#include <hip/hip_runtime.h>
#include <hip/hip_bf16.h>

// Problem constants (fixed by setup_inputs)
#define B_   4
#define N_   4096
#define KNN_ 32
#define KK_  64          // 2*k
#define MTOT 1048576     // B*N*KK
#define BN_EPS 1e-3f

typedef unsigned int u32;
typedef unsigned long long u64;
typedef __attribute__((ext_vector_type(8))) short bf16x8;
typedef __attribute__((ext_vector_type(4))) float f32x4;

__device__ __forceinline__ ushort f2bf_bits(float f) {   // RNE, finite inputs only
    u32 b = __float_as_uint(f);
    b += 0x7fffu + ((b >> 16) & 1u);
    return (ushort)(b >> 16);
}

__device__ __forceinline__ float med3f(float a, float b, float c) {
    return __builtin_amdgcn_fmed3f(a, b, c);
}

// Ranking key with hoisted |c|^2 (czw.y) and premultiplied -2q (3 FMA).
__device__ __forceinline__ float rank_e3(float cx, float cy, float2 zw,
                                         float m2x, float m2y, float m2z) {
    return fmaf(m2x, cx, fmaf(m2y, cy, fmaf(m2z, zw.x, zw.y)));
}

__device__ __forceinline__ u32 ordkey(float f) {         // monotone bijection f32->u32
    u32 u = __float_as_uint(f);
    return u ^ (u32)(((int)u >> 31) | 0x80000000);
}
__device__ __forceinline__ float ordinv(u32 k) {         // exact inverse of ordkey
    u32 u = (k & 0x80000000u) ? (k ^ 0x80000000u) : ~k;
    return __uint_as_float(u);
}

// ---------------------------------------------------------------------------
// K1: dual KNN (r23 verbatim — 196 us measured, parked).
// ---------------------------------------------------------------------------
__global__ __launch_bounds__(512, 2) void knn_kernel(
    const float* __restrict__ p1, const float* __restrict__ p2,
    float* __restrict__ feats, float* __restrict__ mom)
{
    __shared__ float2 cxy[N_];                   // 32 KB (part[] overlaps at end)
    __shared__ float2 czw[N_];                   // 32 KB: (z, |c|^2)

    const int tid  = threadIdx.x;
    const int wave = tid >> 6, lane = tid & 63;
    const int pb    = blockIdx.x >> 6;           // 0..7
    const int chunk = blockIdx.x & 63;           // 0..63
    const int pr = pb >> 2, b = pb & 3;
    const int start = chunk * 64;

    const float* srcb = (pr ? p2 : p1) + (size_t)b * 3 * N_;
    for (int n = tid; n < N_; n += 512) {
        float x = srcb[n], y = srcb[N_ + n], z = srcb[2*N_ + n];
        cxy[n] = make_float2(x, y);
        czw[n] = make_float2(z, fmaf(x, x, fmaf(y, y, z * z)));
    }
    __syncthreads();

    const float* p1b = p1 + (size_t)b * 3 * N_;
    const u64 below = (1ull << lane) - 1ull;
    const float FMAX = 3.402823466e+38f;

    for (int n = start + wave; n < start + 64; n += 8) {
        float qx, qy, qz;
        if (pr == 0) { float2 q = cxy[n]; qx = q.x; qy = q.y; qz = czw[n].x; }
        else         { qx = p1b[n]; qy = p1b[N_ + n]; qz = p1b[2*N_ + n]; }
        const float m2x = -2.0f * qx, m2y = -2.0f * qy, m2z = -2.0f * qz;

        float keys[64];
        float A0 = FMAX, A1 = FMAX, A2 = FMAX, A3 = FMAX;
        float B0 = FMAX, B1 = FMAX, B2 = FMAX, B3 = FMAX;
        #pragma unroll
        for (int j = 0; j < 32; ++j) {
            {
                float2 c  = cxy[j * 64 + lane];
                float2 zw = czw[j * 64 + lane];
                float  e  = rank_e3(c.x, c.y, zw, m2x, m2y, m2z);
                keys[j] = e;
                A3 = med3f(e, A2, A3);
                A2 = med3f(e, A1, A2);
                A1 = med3f(e, A0, A1);
                A0 = fminf(A0, e);
            }
            {
                float2 c  = cxy[(j + 32) * 64 + lane];
                float2 zw = czw[(j + 32) * 64 + lane];
                float  e  = rank_e3(c.x, c.y, zw, m2x, m2y, m2z);
                keys[j + 32] = e;
                B3 = med3f(e, B2, B3);
                B2 = med3f(e, B1, B2);
                B1 = med3f(e, B0, B1);
                B0 = fminf(B0, e);
            }
        }
        #pragma unroll
        for (int m = 0; m < 4; ++m) {
            float x = (m == 0) ? B0 : (m == 1) ? B1 : (m == 2) ? B2 : B3;
            A3 = med3f(x, A2, A3);
            A2 = med3f(x, A1, A2);
            A1 = med3f(x, A0, A1);
            A0 = fminf(A0, x);
        }
        u32 k0 = ordkey(A0), k1 = ordkey(A1), k2 = ordkey(A2), k3 = ordkey(A3);

        u32 mn = k0, mx = k3;
        #pragma unroll
        for (int off = 1; off < 64; off <<= 1) {
            mn = min(mn, (u32)__shfl_xor((int)mn, off, 64));
            mx = max(mx, (u32)__shfl_xor((int)mx, off, 64));
        }
        u32 lo = mn, hi = mx;
        while (lo < hi) {
            u32 mid = lo + ((hi - lo) >> 1);
            int c = __popcll(__ballot(k0 <= mid)) + __popcll(__ballot(k1 <= mid))
                  + __popcll(__ballot(k2 <= mid)) + __popcll(__ballot(k3 <= mid));
            if (c >= 32) hi = mid; else lo = mid + 1;
        }
        u32 T = lo;
        float Tf = ordinv(T);

        int nl;
        if (__ballot(A3 <= Tf) == 0ull) {
            nl = __popcll(__ballot(A0 < Tf)) + __popcll(__ballot(A1 < Tf))
               + __popcll(__ballot(A2 < Tf)) + __popcll(__ballot(A3 < Tf));
        } else {
            nl = 0;
            #pragma unroll
            for (int j = 0; j < 64; ++j) nl += __popcll(__ballot(keys[j] < Tf));
            if (nl > 31) {                  // kept-4 truncated (rare)
                u32 lo2 = 0u, hi2 = T;
                while (lo2 < hi2) {
                    u32 mid = lo2 + ((hi2 - lo2) >> 1);
                    float mf = ordinv(mid);
                    int c = 0;
                    #pragma unroll
                    for (int j = 0; j < 64; ++j) c += __popcll(__ballot(keys[j] <= mf));
                    if (c >= 32) hi2 = mid; else lo2 = mid + 1;
                }
                T = lo2;
                Tf = ordinv(T);
                nl = 0;
                #pragma unroll
                for (int j = 0; j < 64; ++j) nl += __popcll(__ballot(keys[j] < Tf));
            }
        }
        const int need_eq = 32 - nl;        // >= 1; ties resolved by candidate index

        float* fout = feats + ((size_t)(b * N_ + n) * KK_ + pr * KNN_) * 4;
        int base = 0, eq_seen = 0;
        #pragma unroll
        for (int j = 0; j < 64; ++j) {
            float e = keys[j];
            bool lt = e < Tf;
            bool eq = e == Tf;
            u64 mlt = __ballot(lt);
            u64 meq = __ballot(eq);
            if (mlt | meq) {
                int slot = -1;
                if (lt) slot = base + __popcll(mlt & below);
                else if (eq) {
                    int es = eq_seen + __popcll(meq & below);
                    if (es < need_eq) slot = nl + es;
                }
                if (slot >= 0) {
                    float2 c  = cxy[j * 64 + lane];
                    float2 zw = czw[j * 64 + lane];
                    float rx = c.x - qx, ry = c.y - qy, rz = zw.x - qz;
                    float dist = sqrtf(fmaf(rx, rx, fmaf(ry, ry, rz*rz)));
                    *(float4*)(fout + slot * 4) = make_float4(rx, ry, rz, dist);
                }
                base    += __popcll(mlt);
                eq_seen += __popcll(meq);
            }
        }
    }

    // ---- epilogue: moments over this block's own feats (keys dead here) ----
    __syncthreads();
    float mm[14];
    #pragma unroll
    for (int s = 0; s < 14; ++s) mm[s] = 0.f;
    const float4* fb = (const float4*)feats
                     + ((size_t)(b * N_ + start) * KK_ + pr * KNN_);
    for (int idx = tid; idx < 64 * 32; idx += 512) {
        int row = idx >> 5, col = idx & 31;
        float4 f = fb[(size_t)row * KK_ + col];
        float rx = f.x, ry = f.y, rz = f.z, dist = f.w;
        mm[0] += rx; mm[1] += ry; mm[2] += rz; mm[3] += dist;
        mm[4]  = fmaf(rx, rx, mm[4]);   mm[5]  = fmaf(rx, ry, mm[5]);
        mm[6]  = fmaf(rx, rz, mm[6]);   mm[7]  = fmaf(rx, dist, mm[7]);
        mm[8]  = fmaf(ry, ry, mm[8]);   mm[9]  = fmaf(ry, rz, mm[9]);
        mm[10] = fmaf(ry, dist, mm[10]); mm[11] = fmaf(rz, rz, mm[11]);
        mm[12] = fmaf(rz, dist, mm[12]); mm[13] = fmaf(dist, dist, mm[13]);
    }
    #pragma unroll
    for (int s = 0; s < 14; ++s) {
        #pragma unroll
        for (int off = 1; off < 64; off <<= 1) mm[s] += __shfl_xor(mm[s], off, 64);
    }
    float* partf = (float*)cxy;       // cxy dead; barrier above orders reads
    if (lane == 0) {
        #pragma unroll
        for (int s = 0; s < 14; ++s) partf[wave * 14 + s] = mm[s];
    }
    __syncthreads();
    if (tid < 14) {
        float v = 0.f;
        #pragma unroll
        for (int w8 = 0; w8 < 8; ++w8) v += partf[w8 * 14 + tid];
        atomicAdd(&mom[tid * 16], v);    // one cacheline per counter
    }
}

// ---------------------------------------------------------------------------
// K3: MFMA conv2 (r16/r23 form): bn1 from moments, y2 -> bf16 y2F + stats2.
// r18/r24 evidence: conv chain is NOT BW-bound; keep the y2F write.
// ---------------------------------------------------------------------------
__global__ __launch_bounds__(256) void conv2_mfma(
    const float* __restrict__ feats,
    const float* __restrict__ W1,
    const float* __restrict__ g1, const float* __restrict__ be1,
    const float* __restrict__ W2,
    const float* __restrict__ mom,
    ushort* __restrict__ y2F, float* __restrict__ s2S, float* __restrict__ s2Q)
{
    __shared__ float statS[64], statQ[64];
    const int tid = threadIdx.x;
    const int wid = tid >> 6, l = tid & 63, q = l >> 4, i = l & 15;
    if (tid < 64) { statS[tid] = 0.f; statQ[tid] = 0.f; }

    const float invM = 1.0f / MTOT;
    const float M0 = mom[0*16], M1 = mom[1*16], M2 = mom[2*16], M3 = mom[3*16];
    const float Sxx = mom[4*16],  Sxy = mom[5*16],  Sxz = mom[6*16],  Sxd = mom[7*16];
    const float Syy = mom[8*16],  Syz = mom[9*16],  Syd = mom[10*16];
    const float Szz = mom[11*16], Szd = mom[12*16], Sdd = mom[13*16];

    float4 w1f[16];
    float  c1v[16];
    #pragma unroll
    for (int h = 0; h < 2; ++h)
      #pragma unroll
      for (int j = 0; j < 8; ++j) {
        int ci = h*32 + q*8 + j;
        float w0 = W1[ci*4+0], w1 = W1[ci*4+1], w2 = W1[ci*4+2], w3 = W1[ci*4+3];
        float meanf = (w0*M0 + w1*M1 + w2*M2 + w3*M3) * invM;
        float qq = w0*(w0*Sxx + 2.f*(w1*Sxy + w2*Sxz + w3*Sxd))
                 + w1*(w1*Syy + 2.f*(w2*Syz + w3*Syd))
                 + w2*(w2*Szz + 2.f*w3*Szd)
                 + w3*w3*Sdd;
        float var = qq * invM - meanf * meanf;
        float sc  = g1[ci] * rsqrtf(var + BN_EPS);
        w1f[h*8+j] = make_float4(sc*w0, sc*w1, sc*w2, sc*w3);
        c1v[h*8+j] = fmaf(-sc, meanf, be1[ci]);
      }
    bf16x8 a2[4][2];
    #pragma unroll
    for (int t = 0; t < 4; ++t)
      #pragma unroll
      for (int h = 0; h < 2; ++h)
        #pragma unroll
        for (int j = 0; j < 8; ++j)
          a2[t][h][j] = (short)f2bf_bits(W2[(t*16 + i)*64 + h*32 + q*8 + j]);

    float ssum[16], ssq[16];
    #pragma unroll
    for (int s = 0; s < 16; ++s) { ssum[s] = 0.f; ssq[s] = 0.f; }
    __syncthreads();

    for (int r16 = 0; r16 < 16; ++r16) {
        const int row = blockIdx.x * 16 + r16;
        float4 f = ((const float4*)feats)[row*64 + wid*16 + i];
        bf16x8 xb[2];
        #pragma unroll
        for (int h = 0; h < 2; ++h)
          #pragma unroll
          for (int j = 0; j < 8; ++j) {
            float4 w = w1f[h*8+j];
            float x = fmaxf(fmaf(w.x, f.x, fmaf(w.y, f.y, fmaf(w.z, f.z, fmaf(w.w, f.w, c1v[h*8+j])))), 0.f);
            xb[h][j] = (short)f2bf_bits(x);
          }
        f32x4 acc[4];
        #pragma unroll
        for (int t = 0; t < 4; ++t) acc[t] = (f32x4){0.f,0.f,0.f,0.f};
        #pragma unroll
        for (int t = 0; t < 4; ++t) {
            acc[t] = __builtin_amdgcn_mfma_f32_16x16x32_bf16(a2[t][0], xb[0], acc[t], 0, 0, 0);
            acc[t] = __builtin_amdgcn_mfma_f32_16x16x32_bf16(a2[t][1], xb[1], acc[t], 0, 0, 0);
        }
        ushort* wp = y2F + row*4096 + wid*1024 + q*64 + i*4;
        #pragma unroll
        for (int t = 0; t < 4; ++t) {
            #pragma unroll
            for (int reg = 0; reg < 4; ++reg) {
                float y = acc[t][reg];
                ssum[t*4+reg] += y;
                ssq[t*4+reg]  = fmaf(y, y, ssq[t*4+reg]);
            }
            uint2 pk;
            pk.x = (u32)f2bf_bits(acc[t][0]) | ((u32)f2bf_bits(acc[t][1]) << 16);
            pk.y = (u32)f2bf_bits(acc[t][2]) | ((u32)f2bf_bits(acc[t][3]) << 16);
            *(uint2*)(wp + t*256) = pk;
        }
    }
    #pragma unroll
    for (int s = 0; s < 16; ++s) {
        #pragma unroll
        for (int off = 1; off < 16; off <<= 1) {
            ssum[s] += __shfl_xor(ssum[s], off, 64);
            ssq[s]  += __shfl_xor(ssq[s],  off, 64);
        }
    }
    if (i == 0) {
        #pragma unroll
        for (int s = 0; s < 16; ++s) {
            int co = (s >> 2)*16 + q*4 + (s & 3);
            atomicAdd(&statS[co], ssum[s]);
            atomicAdd(&statQ[co], ssq[s]);
        }
    }
    __syncthreads();
    if (tid < 64) { atomicAdd(&s2S[tid], statS[tid]); atomicAdd(&s2Q[tid], statQ[tid]); }
}

// ---------------------------------------------------------------------------
// K4: conv3 stats pass (r25): WAVE-PER-QUARTER. Each wave owns one
// 16-position quarter (w = 0..3) and computes ALL 128 output channels:
// every y2 read, x3 conversion, and in-place x3 write is wave-private ->
// ZERO barriers in the row loop (old form: 16/block + 2x redundant reads;
// the barrier only existed because oh-split waves shared position data).
// x3 bytes and addresses are bit-identical to the old path, so conv3_final
// (unchanged) reads them with the verified frag arithmetic.
// Channel map: t8 = oh*4+t -> co = t8*16+q*4+reg == oh*64+t*16+q*4+reg.
// ---------------------------------------------------------------------------
__global__ __launch_bounds__(256) void conv3_stats(
    ushort* __restrict__ y2F,
    const float* __restrict__ g2, const float* __restrict__ be2,
    const float* __restrict__ W3,
    const float* __restrict__ s2S, const float* __restrict__ s2Q,
    float* __restrict__ s3S, float* __restrict__ s3Q)
{
    __shared__ float statS[128], statQ[128];
    __shared__ float sc2L[64], sh2L[64];
    const int tid = threadIdx.x;
    const int w = tid >> 6, l = tid & 63, q = l >> 4, i = l & 15;
    if (tid < 128) { statS[tid] = 0.f; statQ[tid] = 0.f; }
    if (tid < 64) {                      // bn2 fold -> LDS (saves 32 VGPR)
        float m  = s2S[tid] * (1.0f / MTOT);
        float v  = s2Q[tid] * (1.0f / MTOT) - m * m;
        float sc = g2[tid] * rsqrtf(v + BN_EPS);
        sc2L[tid] = sc;
        sh2L[tid] = fmaf(-sc, m, be2[tid]);
    }

    bf16x8 a3[8][2];                     // all 8 output tiles (both oh halves)
    #pragma unroll
    for (int t8 = 0; t8 < 8; ++t8)
      #pragma unroll
      for (int h = 0; h < 2; ++h)
        #pragma unroll
        for (int j = 0; j < 8; ++j)
          a3[t8][h][j] = (short)f2bf_bits(W3[(t8*16 + i)*64 + h*32 + q*8 + j]);

    float ssum[32], ssq[32];
    #pragma unroll
    for (int s = 0; s < 32; ++s) { ssum[s] = 0.f; ssq[s] = 0.f; }
    __syncthreads();                     // sc2L/statS init visible

    for (int r16 = 0; r16 < 16; ++r16) {
        const int row = blockIdx.x * 16 + r16;
        ushort* rp = y2F + row*4096 + w*1024 + q*128 + i*4;   // wave-private quarter
        uint2 u00 = *(const uint2*)(rp);
        uint2 u01 = *(const uint2*)(rp + 64);
        uint2 u10 = *(const uint2*)(rp + 512);
        uint2 u11 = *(const uint2*)(rp + 576);

        bf16x8 xb[2];
        #pragma unroll
        for (int h = 0; h < 2; ++h) {
            u32 w0 = h ? u10.x : u00.x, w1 = h ? u10.y : u00.y;
            u32 w2 = h ? u11.x : u01.x, w3 = h ? u11.y : u01.y;
            float xf[8];
            xf[0] = __uint_as_float(w0 << 16); xf[1] = __uint_as_float(w0 & 0xffff0000u);
            xf[2] = __uint_as_float(w1 << 16); xf[3] = __uint_as_float(w1 & 0xffff0000u);
            xf[4] = __uint_as_float(w2 << 16); xf[5] = __uint_as_float(w2 & 0xffff0000u);
            xf[6] = __uint_as_float(w3 << 16); xf[7] = __uint_as_float(w3 & 0xffff0000u);
            #pragma unroll
            for (int j = 0; j < 8; ++j) {
                float x = fmaxf(fmaf(sc2L[h*32 + q*8 + j], xf[j], sh2L[h*32 + q*8 + j]), 0.f);
                xb[h][j] = (short)f2bf_bits(x);
            }
        }
        // in-place x3 write — wave-private, mirrors the read packing exactly
        uint4 ub0 = *(uint4*)&xb[0], ub1 = *(uint4*)&xb[1];
        *(uint2*)(rp)       = make_uint2(ub0.x, ub0.y);
        *(uint2*)(rp + 64)  = make_uint2(ub0.z, ub0.w);
        *(uint2*)(rp + 512) = make_uint2(ub1.x, ub1.y);
        *(uint2*)(rp + 576) = make_uint2(ub1.z, ub1.w);

        #pragma unroll
        for (int t8 = 0; t8 < 8; ++t8) {
            f32x4 A = (f32x4){0.f,0.f,0.f,0.f};
            A = __builtin_amdgcn_mfma_f32_16x16x32_bf16(a3[t8][0], xb[0], A, 0, 0, 0);
            A = __builtin_amdgcn_mfma_f32_16x16x32_bf16(a3[t8][1], xb[1], A, 0, 0, 0);
            #pragma unroll
            for (int reg = 0; reg < 4; ++reg) {
                float y = A[reg];
                ssum[t8*4+reg] += y;
                ssq[t8*4+reg]  = fmaf(y, y, ssq[t8*4+reg]);
            }
        }
        // no barrier — next row's data is disjoint and wave-private
    }
    #pragma unroll
    for (int s = 0; s < 32; ++s) {
        #pragma unroll
        for (int off = 1; off < 16; off <<= 1) {
            ssum[s] += __shfl_xor(ssum[s], off, 64);
            ssq[s]  += __shfl_xor(ssq[s],  off, 64);
        }
    }
    if (i == 0) {
        #pragma unroll
        for (int s = 0; s < 32; ++s) {
            int co = (s >> 2)*16 + q*4 + (s & 3);   // t8*16 + q*4 + reg
            atomicAdd(&statS[co], ssum[s]);
            atomicAdd(&statQ[co], ssq[s]);
        }
    }
    __syncthreads();
    if (tid < 128) { atomicAdd(&s3S[tid], statS[tid]); atomicAdd(&s3Q[tid], statQ[tid]); }
}

// ---------------------------------------------------------------------------
// K5: conv3 final pass (r16 form, unchanged). Reads x3F frags DIRECTLY,
// bn3 -> per-half channel max -> LDS combine -> softmax -> weighted sum.
// ---------------------------------------------------------------------------
__global__ __launch_bounds__(256) void conv3_final(
    const ushort* __restrict__ x3F,
    const float* __restrict__ W3,
    const float* __restrict__ g3, const float* __restrict__ be3,
    const float* __restrict__ s3S, const float* __restrict__ s3Q,
    const float4* __restrict__ feats4, const float* __restrict__ p1,
    float* __restrict__ outp)
{
    __shared__ float sc3L[128], sh3L[128];
    __shared__ float s2L[2][2][64];   // [row parity][oh][position]
    const int tid = threadIdx.x;
    const int w = tid >> 6, l = tid & 63, q = l >> 4, i = l & 15;
    const int ph = w >> 1, oh = w & 1;

    if (tid < 128) {
        float m  = s3S[tid] * (1.0f / MTOT);
        float v  = s3Q[tid] * (1.0f / MTOT) - m * m;
        float sc = g3[tid] * rsqrtf(v + BN_EPS);
        sc3L[tid] = sc;
        sh3L[tid] = fmaf(-sc, m, be3[tid]);
    }
    bf16x8 a3[4][2];
    #pragma unroll
    for (int t = 0; t < 4; ++t)
      #pragma unroll
      for (int h = 0; h < 2; ++h)
        #pragma unroll
        for (int j = 0; j < 8; ++j)
          a3[t][h][j] = (short)f2bf_bits(W3[((oh*4 + t)*16 + i)*64 + h*32 + q*8 + j]);
    __syncthreads();

    for (int r16 = 0; r16 < 16; ++r16) {
        const int row = blockIdx.x * 16 + r16;
        #pragma unroll
        for (int pt2 = 0; pt2 < 2; ++pt2) {
            const int pt = 2*ph + pt2;
            const ushort* rp = x3F + row*4096 + pt*1024 + q*128 + i*4;
            uint2 u00 = *(const uint2*)(rp);       uint2 u01 = *(const uint2*)(rp + 64);
            uint2 u10 = *(const uint2*)(rp + 512); uint2 u11 = *(const uint2*)(rp + 576);
            uint4 v0 = make_uint4(u00.x, u00.y, u01.x, u01.y);
            uint4 v1 = make_uint4(u10.x, u10.y, u11.x, u11.y);
            bf16x8 xb0 = *(bf16x8*)&v0, xb1 = *(bf16x8*)&v1;
            float mx = -3.4e38f;
            #pragma unroll
            for (int t = 0; t < 4; ++t) {
                f32x4 a = (f32x4){0.f,0.f,0.f,0.f};
                a = __builtin_amdgcn_mfma_f32_16x16x32_bf16(a3[t][0], xb0, a, 0, 0, 0);
                a = __builtin_amdgcn_mfma_f32_16x16x32_bf16(a3[t][1], xb1, a, 0, 0, 0);
                const int co = oh*64 + t*16 + q*4;
                float4 s4 = *(const float4*)&sc3L[co];
                float4 h4 = *(const float4*)&sh3L[co];
                mx = fmaxf(mx, fmaf(s4.x, a[0], h4.x));
                mx = fmaxf(mx, fmaf(s4.y, a[1], h4.y));
                mx = fmaxf(mx, fmaf(s4.z, a[2], h4.z));
                mx = fmaxf(mx, fmaf(s4.w, a[3], h4.w));
            }
            mx = fmaxf(mx, __shfl_xor(mx, 16, 64));
            mx = fmaxf(mx, __shfl_xor(mx, 32, 64));
            if (q == 0) s2L[r16 & 1][oh][pt*16 + i] = mx;
        }
        __syncthreads();
        if (w == 0) {
            float sc = fmaxf(fmaxf(s2L[r16 & 1][0][l], s2L[r16 & 1][1][l]), 0.f);
            float m2 = sc;
            #pragma unroll
            for (int off = 1; off < 64; off <<= 1) m2 = fmaxf(m2, __shfl_xor(m2, off, 64));
            float e = __expf(sc - m2);
            float se = e;
            #pragma unroll
            for (int off = 1; off < 64; off <<= 1) se += __shfl_xor(se, off, 64);
            float wgt = e / se;
            const int bb = row >> 12, n = row & 4095;
            float qx = p1[(size_t)bb*3*N_ + n];
            float qy = p1[(size_t)bb*3*N_ + N_ + n];
            float qz = p1[(size_t)bb*3*N_ + 2*N_ + n];
            float4 f4 = feats4[row*64 + l];
            float ox = wgt * (f4.x + qx), oy = wgt * (f4.y + qy), oz = wgt * (f4.z + qz);
            #pragma unroll
            for (int off = 1; off < 64; off <<= 1) {
                ox += __shfl_xor(ox, off, 64);
                oy += __shfl_xor(oy, off, 64);
                oz += __shfl_xor(oz, off, 64);
            }
            if (l == 0) {
                outp[bb*3*N_ + 0*N_ + n] = ox;
                outp[bb*3*N_ + 1*N_ + n] = oy;
                outp[bb*3*N_ + 2*N_ + n] = oz;
            }
        }
    }
}

// ---------------------------------------------------------------------------
extern "C" void kernel_launch(void* const* d_in, const int* in_sizes, int n_in,
                              void* d_out, int out_size, void* d_ws, size_t ws_size,
                              hipStream_t stream)
{
    const float* p1  = (const float*)d_in[0];
    const float* p2  = (const float*)d_in[1];
    // d_in[2] = k (always 32), d_in[3] = t (unused by reference)
    const float* W1  = (const float*)d_in[4];
    const float* g1  = (const float*)d_in[6];
    const float* be1 = (const float*)d_in[7];
    const float* W2  = (const float*)d_in[8];
    const float* g2  = (const float*)d_in[10];
    const float* be2 = (const float*)d_in[11];
    const float* W3  = (const float*)d_in[12];
    const float* g3  = (const float*)d_in[14];
    const float* be3 = (const float*)d_in[15];
    // b1 cancels through bn1 (moment fold); b2/b3 cancel through bn2/bn3.

    char* ws = (char*)d_ws;
    const size_t OFF_FEATS = 4096;
    const size_t OFF_Y2    = OFF_FEATS + (size_t)MTOT * 4 * 4;          // 16 MB feats
    const size_t NEEDED    = OFF_Y2 + (size_t)MTOT * 64 * 2;            // 128 MB y2/x3
    if (ws_size < NEEDED) return;  // fail visibly (wrong output) rather than fault

    float* s2S = (float*)(ws + 512);  float* s2Q = (float*)(ws + 768);
    float* s3S = (float*)(ws + 1024); float* s3Q = (float*)(ws + 1536);
    float* mom = (float*)(ws + 2048);            // 14 counters, 64-B stride each
    float* feats = (float*)(ws + OFF_FEATS);
    ushort* y2F  = (ushort*)(ws + OFF_Y2);       // y2 frags, overwritten with x3

    hipMemsetAsync(ws, 0, 4096, stream);  // zero stats + padded moment counters

    knn_kernel<<<512, 512, 0, stream>>>(p1, p2, feats, mom);
    conv2_mfma<<<1024, 256, 0, stream>>>(feats, W1, g1, be1, W2, mom,
                                         y2F, s2S, s2Q);
    conv3_stats<<<1024, 256, 0, stream>>>(y2F, g2, be2, W3,
                                          s2S, s2Q, s3S, s3Q);
    conv3_final<<<1024, 256, 0, stream>>>(y2F, W3, g3, be3, s3S, s3Q,
                                          (const float4*)feats, p1,
                                          (float*)d_out);
}

// Round 15
// 417.855 us; speedup vs baseline: 1.1946x; 1.0448x over previous
//
#include <hip/hip_runtime.h>
#include <hip/hip_bf16.h>

// Problem constants (fixed by setup_inputs)
#define B_   4
#define N_   4096
#define KNN_ 32
#define KK_  64          // 2*k
#define MTOT 1048576     // B*N*KK
#define BN_EPS 1e-3f

typedef unsigned int u32;
typedef unsigned long long u64;
typedef __attribute__((ext_vector_type(8))) short bf16x8;
typedef __attribute__((ext_vector_type(4))) float f32x4;

__device__ __forceinline__ ushort f2bf_bits(float f) {   // RNE, finite inputs only
    u32 b = __float_as_uint(f);
    b += 0x7fffu + ((b >> 16) & 1u);
    return (ushort)(b >> 16);
}

__device__ __forceinline__ float med3f(float a, float b, float c) {
    return __builtin_amdgcn_fmed3f(a, b, c);
}

// Ranking key with hoisted |c|^2 (czw.y) and premultiplied -2q (3 FMA).
__device__ __forceinline__ float rank_e3(float cx, float cy, float2 zw,
                                         float m2x, float m2y, float m2z) {
    return fmaf(m2x, cx, fmaf(m2y, cy, fmaf(m2z, zw.x, zw.y)));
}

__device__ __forceinline__ u32 ordkey(float f) {         // monotone bijection f32->u32
    u32 u = __float_as_uint(f);
    return u ^ (u32)(((int)u >> 31) | 0x80000000);
}
__device__ __forceinline__ float ordinv(u32 k) {         // exact inverse of ordkey
    u32 u = (k & 0x80000000u) ? (k ^ 0x80000000u) : ~k;
    return __uint_as_float(u);
}

// ---------------------------------------------------------------------------
// K1: dual KNN (r23 form — session best, 196 us measured). float keys in
// registers, med3 kept-4 chains, cw-hoisted 3-FMA rank key, LDS exactly
// 65536 B (cxy + czw; epilogue part[] overlapped into dead cxy), moments
// as an epilogue over the block's own L2-hot feats. Parked: VALU floor
// ~114 us, bound by serial ballot/scalar chains, remaining levers <5%.
// ---------------------------------------------------------------------------
__global__ __launch_bounds__(512, 2) void knn_kernel(
    const float* __restrict__ p1, const float* __restrict__ p2,
    float* __restrict__ feats, float* __restrict__ mom)
{
    __shared__ float2 cxy[N_];                   // 32 KB (part[] overlaps at end)
    __shared__ float2 czw[N_];                   // 32 KB: (z, |c|^2)

    const int tid  = threadIdx.x;
    const int wave = tid >> 6, lane = tid & 63;
    const int pb    = blockIdx.x >> 6;           // 0..7
    const int chunk = blockIdx.x & 63;           // 0..63
    const int pr = pb >> 2, b = pb & 3;
    const int start = chunk * 64;

    const float* srcb = (pr ? p2 : p1) + (size_t)b * 3 * N_;
    for (int n = tid; n < N_; n += 512) {
        float x = srcb[n], y = srcb[N_ + n], z = srcb[2*N_ + n];
        cxy[n] = make_float2(x, y);
        czw[n] = make_float2(z, fmaf(x, x, fmaf(y, y, z * z)));
    }
    __syncthreads();

    const float* p1b = p1 + (size_t)b * 3 * N_;
    const u64 below = (1ull << lane) - 1ull;
    const float FMAX = 3.402823466e+38f;

    for (int n = start + wave; n < start + 64; n += 8) {
        float qx, qy, qz;
        if (pr == 0) { float2 q = cxy[n]; qx = q.x; qy = q.y; qz = czw[n].x; }
        else         { qx = p1b[n]; qy = p1b[N_ + n]; qz = p1b[2*N_ + n]; }
        const float m2x = -2.0f * qx, m2y = -2.0f * qy, m2z = -2.0f * qz;

        float keys[64];
        float A0 = FMAX, A1 = FMAX, A2 = FMAX, A3 = FMAX;
        float B0 = FMAX, B1 = FMAX, B2 = FMAX, B3 = FMAX;
        #pragma unroll
        for (int j = 0; j < 32; ++j) {
            {
                float2 c  = cxy[j * 64 + lane];
                float2 zw = czw[j * 64 + lane];
                float  e  = rank_e3(c.x, c.y, zw, m2x, m2y, m2z);
                keys[j] = e;
                A3 = med3f(e, A2, A3);
                A2 = med3f(e, A1, A2);
                A1 = med3f(e, A0, A1);
                A0 = fminf(A0, e);
            }
            {
                float2 c  = cxy[(j + 32) * 64 + lane];
                float2 zw = czw[(j + 32) * 64 + lane];
                float  e  = rank_e3(c.x, c.y, zw, m2x, m2y, m2z);
                keys[j + 32] = e;
                B3 = med3f(e, B2, B3);
                B2 = med3f(e, B1, B2);
                B1 = med3f(e, B0, B1);
                B0 = fminf(B0, e);
            }
        }
        #pragma unroll
        for (int m = 0; m < 4; ++m) {
            float x = (m == 0) ? B0 : (m == 1) ? B1 : (m == 2) ? B2 : B3;
            A3 = med3f(x, A2, A3);
            A2 = med3f(x, A1, A2);
            A1 = med3f(x, A0, A1);
            A0 = fminf(A0, x);
        }
        u32 k0 = ordkey(A0), k1 = ordkey(A1), k2 = ordkey(A2), k3 = ordkey(A3);

        u32 mn = k0, mx = k3;
        #pragma unroll
        for (int off = 1; off < 64; off <<= 1) {
            mn = min(mn, (u32)__shfl_xor((int)mn, off, 64));
            mx = max(mx, (u32)__shfl_xor((int)mx, off, 64));
        }
        u32 lo = mn, hi = mx;
        while (lo < hi) {
            u32 mid = lo + ((hi - lo) >> 1);
            int c = __popcll(__ballot(k0 <= mid)) + __popcll(__ballot(k1 <= mid))
                  + __popcll(__ballot(k2 <= mid)) + __popcll(__ballot(k3 <= mid));
            if (c >= 32) hi = mid; else lo = mid + 1;
        }
        u32 T = lo;
        float Tf = ordinv(T);

        int nl;
        if (__ballot(A3 <= Tf) == 0ull) {
            nl = __popcll(__ballot(A0 < Tf)) + __popcll(__ballot(A1 < Tf))
               + __popcll(__ballot(A2 < Tf)) + __popcll(__ballot(A3 < Tf));
        } else {
            nl = 0;
            #pragma unroll
            for (int j = 0; j < 64; ++j) nl += __popcll(__ballot(keys[j] < Tf));
            if (nl > 31) {                  // kept-4 truncated (rare)
                u32 lo2 = 0u, hi2 = T;
                while (lo2 < hi2) {
                    u32 mid = lo2 + ((hi2 - lo2) >> 1);
                    float mf = ordinv(mid);
                    int c = 0;
                    #pragma unroll
                    for (int j = 0; j < 64; ++j) c += __popcll(__ballot(keys[j] <= mf));
                    if (c >= 32) hi2 = mid; else lo2 = mid + 1;
                }
                T = lo2;
                Tf = ordinv(T);
                nl = 0;
                #pragma unroll
                for (int j = 0; j < 64; ++j) nl += __popcll(__ballot(keys[j] < Tf));
            }
        }
        const int need_eq = 32 - nl;        // >= 1; ties resolved by candidate index

        float* fout = feats + ((size_t)(b * N_ + n) * KK_ + pr * KNN_) * 4;
        int base = 0, eq_seen = 0;
        #pragma unroll
        for (int j = 0; j < 64; ++j) {
            float e = keys[j];
            bool lt = e < Tf;
            bool eq = e == Tf;
            u64 mlt = __ballot(lt);
            u64 meq = __ballot(eq);
            if (mlt | meq) {
                int slot = -1;
                if (lt) slot = base + __popcll(mlt & below);
                else if (eq) {
                    int es = eq_seen + __popcll(meq & below);
                    if (es < need_eq) slot = nl + es;
                }
                if (slot >= 0) {
                    float2 c  = cxy[j * 64 + lane];
                    float2 zw = czw[j * 64 + lane];
                    float rx = c.x - qx, ry = c.y - qy, rz = zw.x - qz;
                    float dist = sqrtf(fmaf(rx, rx, fmaf(ry, ry, rz*rz)));
                    *(float4*)(fout + slot * 4) = make_float4(rx, ry, rz, dist);
                }
                base    += __popcll(mlt);
                eq_seen += __popcll(meq);
            }
        }
    }

    // ---- epilogue: moments over this block's own feats (keys dead here) ----
    __syncthreads();
    float mm[14];
    #pragma unroll
    for (int s = 0; s < 14; ++s) mm[s] = 0.f;
    const float4* fb = (const float4*)feats
                     + ((size_t)(b * N_ + start) * KK_ + pr * KNN_);
    for (int idx = tid; idx < 64 * 32; idx += 512) {
        int row = idx >> 5, col = idx & 31;
        float4 f = fb[(size_t)row * KK_ + col];
        float rx = f.x, ry = f.y, rz = f.z, dist = f.w;
        mm[0] += rx; mm[1] += ry; mm[2] += rz; mm[3] += dist;
        mm[4]  = fmaf(rx, rx, mm[4]);   mm[5]  = fmaf(rx, ry, mm[5]);
        mm[6]  = fmaf(rx, rz, mm[6]);   mm[7]  = fmaf(rx, dist, mm[7]);
        mm[8]  = fmaf(ry, ry, mm[8]);   mm[9]  = fmaf(ry, rz, mm[9]);
        mm[10] = fmaf(ry, dist, mm[10]); mm[11] = fmaf(rz, rz, mm[11]);
        mm[12] = fmaf(rz, dist, mm[12]); mm[13] = fmaf(dist, dist, mm[13]);
    }
    #pragma unroll
    for (int s = 0; s < 14; ++s) {
        #pragma unroll
        for (int off = 1; off < 64; off <<= 1) mm[s] += __shfl_xor(mm[s], off, 64);
    }
    float* partf = (float*)cxy;       // cxy dead; barrier above orders reads
    if (lane == 0) {
        #pragma unroll
        for (int s = 0; s < 14; ++s) partf[wave * 14 + s] = mm[s];
    }
    __syncthreads();
    if (tid < 14) {
        float v = 0.f;
        #pragma unroll
        for (int w8 = 0; w8 < 8; ++w8) v += partf[w8 * 14 + tid];
        atomicAdd(&mom[tid * 16], v);    // one cacheline per counter
    }
}

// ---------------------------------------------------------------------------
// K3: MFMA conv2 (r16/r23 form): bn1 from moments, y2 -> bf16 y2F + stats2.
// r18/r24 evidence: conv chain is NOT BW-bound; keep the y2F write.
// ---------------------------------------------------------------------------
__global__ __launch_bounds__(256) void conv2_mfma(
    const float* __restrict__ feats,
    const float* __restrict__ W1,
    const float* __restrict__ g1, const float* __restrict__ be1,
    const float* __restrict__ W2,
    const float* __restrict__ mom,
    ushort* __restrict__ y2F, float* __restrict__ s2S, float* __restrict__ s2Q)
{
    __shared__ float statS[64], statQ[64];
    const int tid = threadIdx.x;
    const int wid = tid >> 6, l = tid & 63, q = l >> 4, i = l & 15;
    if (tid < 64) { statS[tid] = 0.f; statQ[tid] = 0.f; }

    const float invM = 1.0f / MTOT;
    const float M0 = mom[0*16], M1 = mom[1*16], M2 = mom[2*16], M3 = mom[3*16];
    const float Sxx = mom[4*16],  Sxy = mom[5*16],  Sxz = mom[6*16],  Sxd = mom[7*16];
    const float Syy = mom[8*16],  Syz = mom[9*16],  Syd = mom[10*16];
    const float Szz = mom[11*16], Szd = mom[12*16], Sdd = mom[13*16];

    float4 w1f[16];
    float  c1v[16];
    #pragma unroll
    for (int h = 0; h < 2; ++h)
      #pragma unroll
      for (int j = 0; j < 8; ++j) {
        int ci = h*32 + q*8 + j;
        float w0 = W1[ci*4+0], w1 = W1[ci*4+1], w2 = W1[ci*4+2], w3 = W1[ci*4+3];
        float meanf = (w0*M0 + w1*M1 + w2*M2 + w3*M3) * invM;
        float qq = w0*(w0*Sxx + 2.f*(w1*Sxy + w2*Sxz + w3*Sxd))
                 + w1*(w1*Syy + 2.f*(w2*Syz + w3*Syd))
                 + w2*(w2*Szz + 2.f*w3*Szd)
                 + w3*w3*Sdd;
        float var = qq * invM - meanf * meanf;
        float sc  = g1[ci] * rsqrtf(var + BN_EPS);
        w1f[h*8+j] = make_float4(sc*w0, sc*w1, sc*w2, sc*w3);
        c1v[h*8+j] = fmaf(-sc, meanf, be1[ci]);
      }
    bf16x8 a2[4][2];
    #pragma unroll
    for (int t = 0; t < 4; ++t)
      #pragma unroll
      for (int h = 0; h < 2; ++h)
        #pragma unroll
        for (int j = 0; j < 8; ++j)
          a2[t][h][j] = (short)f2bf_bits(W2[(t*16 + i)*64 + h*32 + q*8 + j]);

    float ssum[16], ssq[16];
    #pragma unroll
    for (int s = 0; s < 16; ++s) { ssum[s] = 0.f; ssq[s] = 0.f; }
    __syncthreads();

    for (int r16 = 0; r16 < 16; ++r16) {
        const int row = blockIdx.x * 16 + r16;
        float4 f = ((const float4*)feats)[row*64 + wid*16 + i];
        bf16x8 xb[2];
        #pragma unroll
        for (int h = 0; h < 2; ++h)
          #pragma unroll
          for (int j = 0; j < 8; ++j) {
            float4 w = w1f[h*8+j];
            float x = fmaxf(fmaf(w.x, f.x, fmaf(w.y, f.y, fmaf(w.z, f.z, fmaf(w.w, f.w, c1v[h*8+j])))), 0.f);
            xb[h][j] = (short)f2bf_bits(x);
          }
        f32x4 acc[4];
        #pragma unroll
        for (int t = 0; t < 4; ++t) acc[t] = (f32x4){0.f,0.f,0.f,0.f};
        #pragma unroll
        for (int t = 0; t < 4; ++t) {
            acc[t] = __builtin_amdgcn_mfma_f32_16x16x32_bf16(a2[t][0], xb[0], acc[t], 0, 0, 0);
            acc[t] = __builtin_amdgcn_mfma_f32_16x16x32_bf16(a2[t][1], xb[1], acc[t], 0, 0, 0);
        }
        ushort* wp = y2F + row*4096 + wid*1024 + q*64 + i*4;
        #pragma unroll
        for (int t = 0; t < 4; ++t) {
            #pragma unroll
            for (int reg = 0; reg < 4; ++reg) {
                float y = acc[t][reg];
                ssum[t*4+reg] += y;
                ssq[t*4+reg]  = fmaf(y, y, ssq[t*4+reg]);
            }
            uint2 pk;
            pk.x = (u32)f2bf_bits(acc[t][0]) | ((u32)f2bf_bits(acc[t][1]) << 16);
            pk.y = (u32)f2bf_bits(acc[t][2]) | ((u32)f2bf_bits(acc[t][3]) << 16);
            *(uint2*)(wp + t*256) = pk;
        }
    }
    #pragma unroll
    for (int s = 0; s < 16; ++s) {
        #pragma unroll
        for (int off = 1; off < 16; off <<= 1) {
            ssum[s] += __shfl_xor(ssum[s], off, 64);
            ssq[s]  += __shfl_xor(ssq[s],  off, 64);
        }
    }
    if (i == 0) {
        #pragma unroll
        for (int s = 0; s < 16; ++s) {
            int co = (s >> 2)*16 + q*4 + (s & 3);
            atomicAdd(&statS[co], ssum[s]);
            atomicAdd(&statQ[co], ssq[s]);
        }
    }
    __syncthreads();
    if (tid < 64) { atomicAdd(&s2S[tid], statS[tid]); atomicAdd(&s2Q[tid], statQ[tid]); }
}

// ---------------------------------------------------------------------------
// K4: conv3 stats pass (r16 form), wave-split by (pos-half ph, out-ch-half oh).
// Reads y2 frags, builds x3 = relu(bn2(y2)), writes x3 back IN PLACE over
// y2F (oh==0 waves; per-row barrier makes it race-free), accumulates stats3.
// r25 evidence: barrier-free variant is neutral (barriers hidden by overlap).
// ---------------------------------------------------------------------------
__global__ __launch_bounds__(256) void conv3_stats(
    ushort* __restrict__ y2F,
    const float* __restrict__ g2, const float* __restrict__ be2,
    const float* __restrict__ W3,
    const float* __restrict__ s2S, const float* __restrict__ s2Q,
    float* __restrict__ s3S, float* __restrict__ s3Q)
{
    __shared__ float statS[128], statQ[128];
    const int tid = threadIdx.x;
    const int w = tid >> 6, l = tid & 63, q = l >> 4, i = l & 15;
    const int ph = w >> 1, oh = w & 1;
    if (tid < 128) { statS[tid] = 0.f; statQ[tid] = 0.f; }

    float sc2v[16], sh2v[16];
    #pragma unroll
    for (int h = 0; h < 2; ++h)
      #pragma unroll
      for (int j = 0; j < 8; ++j) {
        int ci = h*32 + q*8 + j;
        float m  = s2S[ci] * (1.0f / MTOT);
        float v  = s2Q[ci] * (1.0f / MTOT) - m * m;
        float sc = g2[ci] * rsqrtf(v + BN_EPS);
        sc2v[h*8+j] = sc;
        sh2v[h*8+j] = fmaf(-sc, m, be2[ci]);
      }
    bf16x8 a3[4][2];
    #pragma unroll
    for (int t = 0; t < 4; ++t)
      #pragma unroll
      for (int h = 0; h < 2; ++h)
        #pragma unroll
        for (int j = 0; j < 8; ++j)
          a3[t][h][j] = (short)f2bf_bits(W3[((oh*4 + t)*16 + i)*64 + h*32 + q*8 + j]);

    float ssum[16], ssq[16];
    #pragma unroll
    for (int s = 0; s < 16; ++s) { ssum[s] = 0.f; ssq[s] = 0.f; }

    for (int r16 = 0; r16 < 16; ++r16) {
        const int row = blockIdx.x * 16 + r16;
        ushort* rp0 = y2F + row*4096 + (2*ph)*1024 + q*128 + i*4;
        ushort* rp1 = rp0 + 1024;
        uint2 a00 = *(const uint2*)(rp0);       uint2 a01 = *(const uint2*)(rp0 + 64);
        uint2 a10 = *(const uint2*)(rp0 + 512); uint2 a11 = *(const uint2*)(rp0 + 576);
        uint2 b00 = *(const uint2*)(rp1);       uint2 b01 = *(const uint2*)(rp1 + 64);
        uint2 b10 = *(const uint2*)(rp1 + 512); uint2 b11 = *(const uint2*)(rp1 + 576);

        bf16x8 xa[2], xc[2];
        #pragma unroll
        for (int pt2 = 0; pt2 < 2; ++pt2) {
            uint2 v00 = pt2 ? b00 : a00, v01 = pt2 ? b01 : a01;
            uint2 v10 = pt2 ? b10 : a10, v11 = pt2 ? b11 : a11;
            bf16x8* dst = pt2 ? xc : xa;
            #pragma unroll
            for (int h = 0; h < 2; ++h) {
                u32 w0 = h ? v10.x : v00.x, w1 = h ? v10.y : v00.y;
                u32 w2 = h ? v11.x : v01.x, w3 = h ? v11.y : v01.y;
                float xf[8];
                xf[0] = __uint_as_float(w0 << 16); xf[1] = __uint_as_float(w0 & 0xffff0000u);
                xf[2] = __uint_as_float(w1 << 16); xf[3] = __uint_as_float(w1 & 0xffff0000u);
                xf[4] = __uint_as_float(w2 << 16); xf[5] = __uint_as_float(w2 & 0xffff0000u);
                xf[6] = __uint_as_float(w3 << 16); xf[7] = __uint_as_float(w3 & 0xffff0000u);
                #pragma unroll
                for (int j = 0; j < 8; ++j) {
                    float x = fmaxf(fmaf(sc2v[h*8+j], xf[j], sh2v[h*8+j]), 0.f);
                    dst[h][j] = (short)f2bf_bits(x);
                }
            }
        }
        __syncthreads();     // all reads of this row drained before overwrite
        if (oh == 0) {       // in-place x3 write (frag layout preserved)
            uint4 ua0 = *(uint4*)&xa[0], ua1 = *(uint4*)&xa[1];
            uint4 uc0 = *(uint4*)&xc[0], uc1 = *(uint4*)&xc[1];
            *(uint2*)(rp0)       = make_uint2(ua0.x, ua0.y);
            *(uint2*)(rp0 + 64)  = make_uint2(ua0.z, ua0.w);
            *(uint2*)(rp0 + 512) = make_uint2(ua1.x, ua1.y);
            *(uint2*)(rp0 + 576) = make_uint2(ua1.z, ua1.w);
            *(uint2*)(rp1)       = make_uint2(uc0.x, uc0.y);
            *(uint2*)(rp1 + 64)  = make_uint2(uc0.z, uc0.w);
            *(uint2*)(rp1 + 512) = make_uint2(uc1.x, uc1.y);
            *(uint2*)(rp1 + 576) = make_uint2(uc1.z, uc1.w);
        }
        #pragma unroll
        for (int t = 0; t < 4; ++t) {
            f32x4 A = (f32x4){0.f,0.f,0.f,0.f};
            A = __builtin_amdgcn_mfma_f32_16x16x32_bf16(a3[t][0], xa[0], A, 0, 0, 0);
            A = __builtin_amdgcn_mfma_f32_16x16x32_bf16(a3[t][1], xa[1], A, 0, 0, 0);
            f32x4 Bv = (f32x4){0.f,0.f,0.f,0.f};
            Bv = __builtin_amdgcn_mfma_f32_16x16x32_bf16(a3[t][0], xc[0], Bv, 0, 0, 0);
            Bv = __builtin_amdgcn_mfma_f32_16x16x32_bf16(a3[t][1], xc[1], Bv, 0, 0, 0);
            #pragma unroll
            for (int reg = 0; reg < 4; ++reg) {
                float ya = A[reg], yb = Bv[reg];
                ssum[t*4+reg] += ya + yb;
                ssq[t*4+reg]  = fmaf(ya, ya, fmaf(yb, yb, ssq[t*4+reg]));
            }
        }
    }
    #pragma unroll
    for (int s = 0; s < 16; ++s) {
        #pragma unroll
        for (int off = 1; off < 16; off <<= 1) {
            ssum[s] += __shfl_xor(ssum[s], off, 64);
            ssq[s]  += __shfl_xor(ssq[s],  off, 64);
        }
    }
    if (i == 0) {
        #pragma unroll
        for (int s = 0; s < 16; ++s) {
            int co = oh*64 + (s >> 2)*16 + q*4 + (s & 3);
            atomicAdd(&statS[co], ssum[s]);
            atomicAdd(&statQ[co], ssq[s]);
        }
    }
    __syncthreads();
    if (tid < 128) { atomicAdd(&s3S[tid], statS[tid]); atomicAdd(&s3Q[tid], statQ[tid]); }
}

// ---------------------------------------------------------------------------
// K5: conv3 final pass (r16 form), wave-split. Reads x3F frags DIRECTLY,
// bn3 -> per-half channel max -> LDS combine -> softmax -> weighted sum.
// ---------------------------------------------------------------------------
__global__ __launch_bounds__(256) void conv3_final(
    const ushort* __restrict__ x3F,
    const float* __restrict__ W3,
    const float* __restrict__ g3, const float* __restrict__ be3,
    const float* __restrict__ s3S, const float* __restrict__ s3Q,
    const float4* __restrict__ feats4, const float* __restrict__ p1,
    float* __restrict__ outp)
{
    __shared__ float sc3L[128], sh3L[128];
    __shared__ float s2L[2][2][64];   // [row parity][oh][position]
    const int tid = threadIdx.x;
    const int w = tid >> 6, l = tid & 63, q = l >> 4, i = l & 15;
    const int ph = w >> 1, oh = w & 1;

    if (tid < 128) {
        float m  = s3S[tid] * (1.0f / MTOT);
        float v  = s3Q[tid] * (1.0f / MTOT) - m * m;
        float sc = g3[tid] * rsqrtf(v + BN_EPS);
        sc3L[tid] = sc;
        sh3L[tid] = fmaf(-sc, m, be3[tid]);
    }
    bf16x8 a3[4][2];
    #pragma unroll
    for (int t = 0; t < 4; ++t)
      #pragma unroll
      for (int h = 0; h < 2; ++h)
        #pragma unroll
        for (int j = 0; j < 8; ++j)
          a3[t][h][j] = (short)f2bf_bits(W3[((oh*4 + t)*16 + i)*64 + h*32 + q*8 + j]);
    __syncthreads();

    for (int r16 = 0; r16 < 16; ++r16) {
        const int row = blockIdx.x * 16 + r16;
        #pragma unroll
        for (int pt2 = 0; pt2 < 2; ++pt2) {
            const int pt = 2*ph + pt2;
            const ushort* rp = x3F + row*4096 + pt*1024 + q*128 + i*4;
            uint2 u00 = *(const uint2*)(rp);       uint2 u01 = *(const uint2*)(rp + 64);
            uint2 u10 = *(const uint2*)(rp + 512); uint2 u11 = *(const uint2*)(rp + 576);
            uint4 v0 = make_uint4(u00.x, u00.y, u01.x, u01.y);
            uint4 v1 = make_uint4(u10.x, u10.y, u11.x, u11.y);
            bf16x8 xb0 = *(bf16x8*)&v0, xb1 = *(bf16x8*)&v1;
            float mx = -3.4e38f;
            #pragma unroll
            for (int t = 0; t < 4; ++t) {
                f32x4 a = (f32x4){0.f,0.f,0.f,0.f};
                a = __builtin_amdgcn_mfma_f32_16x16x32_bf16(a3[t][0], xb0, a, 0, 0, 0);
                a = __builtin_amdgcn_mfma_f32_16x16x32_bf16(a3[t][1], xb1, a, 0, 0, 0);
                const int co = oh*64 + t*16 + q*4;
                float4 s4 = *(const float4*)&sc3L[co];
                float4 h4 = *(const float4*)&sh3L[co];
                mx = fmaxf(mx, fmaf(s4.x, a[0], h4.x));
                mx = fmaxf(mx, fmaf(s4.y, a[1], h4.y));
                mx = fmaxf(mx, fmaf(s4.z, a[2], h4.z));
                mx = fmaxf(mx, fmaf(s4.w, a[3], h4.w));
            }
            mx = fmaxf(mx, __shfl_xor(mx, 16, 64));
            mx = fmaxf(mx, __shfl_xor(mx, 32, 64));
            if (q == 0) s2L[r16 & 1][oh][pt*16 + i] = mx;
        }
        __syncthreads();
        if (w == 0) {
            float sc = fmaxf(fmaxf(s2L[r16 & 1][0][l], s2L[r16 & 1][1][l]), 0.f);
            float m2 = sc;
            #pragma unroll
            for (int off = 1; off < 64; off <<= 1) m2 = fmaxf(m2, __shfl_xor(m2, off, 64));
            float e = __expf(sc - m2);
            float se = e;
            #pragma unroll
            for (int off = 1; off < 64; off <<= 1) se += __shfl_xor(se, off, 64);
            float wgt = e / se;
            const int bb = row >> 12, n = row & 4095;
            float qx = p1[(size_t)bb*3*N_ + n];
            float qy = p1[(size_t)bb*3*N_ + N_ + n];
            float qz = p1[(size_t)bb*3*N_ + 2*N_ + n];
            float4 f4 = feats4[row*64 + l];
            float ox = wgt * (f4.x + qx), oy = wgt * (f4.y + qy), oz = wgt * (f4.z + qz);
            #pragma unroll
            for (int off = 1; off < 64; off <<= 1) {
                ox += __shfl_xor(ox, off, 64);
                oy += __shfl_xor(oy, off, 64);
                oz += __shfl_xor(oz, off, 64);
            }
            if (l == 0) {
                outp[bb*3*N_ + 0*N_ + n] = ox;
                outp[bb*3*N_ + 1*N_ + n] = oy;
                outp[bb*3*N_ + 2*N_ + n] = oz;
            }
        }
    }
}

// ---------------------------------------------------------------------------
extern "C" void kernel_launch(void* const* d_in, const int* in_sizes, int n_in,
                              void* d_out, int out_size, void* d_ws, size_t ws_size,
                              hipStream_t stream)
{
    const float* p1  = (const float*)d_in[0];
    const float* p2  = (const float*)d_in[1];
    // d_in[2] = k (always 32), d_in[3] = t (unused by reference)
    const float* W1  = (const float*)d_in[4];
    const float* g1  = (const float*)d_in[6];
    const float* be1 = (const float*)d_in[7];
    const float* W2  = (const float*)d_in[8];
    const float* g2  = (const float*)d_in[10];
    const float* be2 = (const float*)d_in[11];
    const float* W3  = (const float*)d_in[12];
    const float* g3  = (const float*)d_in[14];
    const float* be3 = (const float*)d_in[15];
    // b1 cancels through bn1 (moment fold); b2/b3 cancel through bn2/bn3.

    char* ws = (char*)d_ws;
    const size_t OFF_FEATS = 4096;
    const size_t OFF_Y2    = OFF_FEATS + (size_t)MTOT * 4 * 4;          // 16 MB feats
    const size_t NEEDED    = OFF_Y2 + (size_t)MTOT * 64 * 2;            // 128 MB y2/x3
    if (ws_size < NEEDED) return;  // fail visibly (wrong output) rather than fault

    float* s2S = (float*)(ws + 512);  float* s2Q = (float*)(ws + 768);
    float* s3S = (float*)(ws + 1024); float* s3Q = (float*)(ws + 1536);
    float* mom = (float*)(ws + 2048);            // 14 counters, 64-B stride each
    float* feats = (float*)(ws + OFF_FEATS);
    ushort* y2F  = (ushort*)(ws + OFF_Y2);       // y2 frags, overwritten with x3

    hipMemsetAsync(ws, 0, 4096, stream);  // zero stats + padded moment counters

    knn_kernel<<<512, 512, 0, stream>>>(p1, p2, feats, mom);
    conv2_mfma<<<1024, 256, 0, stream>>>(feats, W1, g1, be1, W2, mom,
                                         y2F, s2S, s2Q);
    conv3_stats<<<1024, 256, 0, stream>>>(y2F, g2, be2, W3,
                                          s2S, s2Q, s3S, s3Q);
    conv3_final<<<1024, 256, 0, stream>>>(y2F, W3, g3, be3, s3S, s3Q,
                                          (const float4*)feats, p1,
                                          (float*)d_out);
}